// Round 14
// baseline (4202.656 us; speedup 1.0000x reference)
//
#include <hip/hip_runtime.h>

#define NB 128      // batch
#define NT 8192     // time steps
#define NS 128      // states
#define NE 6        // alphabet

typedef __attribute__((ext_vector_type(8))) short bf16x8;     // 8 bf16 (4 VGPRs)
typedef __attribute__((ext_vector_type(4))) float f32x4;      // MFMA accumulator
typedef __attribute__((ext_vector_type(4))) int   int32x4;
typedef __attribute__((ext_vector_type(2))) unsigned uint32x2;

#define MFMA __builtin_amdgcn_mfma_f32_16x16x32_bf16

// fp32 -> bf16 RNE (for the one-time A conversion)
__device__ __forceinline__ short f2bf(float v) {
    unsigned u = __float_as_uint(v);
    u += 0x7fffu + ((u >> 16) & 1u);
    return (short)(u >> 16);
}
// packed fp32x2 -> bf16x2 RNE (1 instr for 2 values; no builtin on gfx950)
__device__ __forceinline__ unsigned cvtpk(float lo, float hi) {
    unsigned r;
    asm("v_cvt_pk_bf16_f32 %0, %1, %2" : "=v"(r) : "v"(lo), "v"(hi));
    return r;
}

// pack 8 symbols (values 0..5) into one u32, 4 bits each
#define PACK8(a, b)                                                          \
    ((unsigned)((a)[0] & 7)        | ((unsigned)((a)[1] & 7) << 4) |         \
     ((unsigned)((a)[2] & 7) << 8) | ((unsigned)((a)[3] & 7) << 12) |        \
     ((unsigned)((b)[0] & 7) << 16)| ((unsigned)((b)[1] & 7) << 20) |        \
     ((unsigned)((b)[2] & 7) << 24)| ((unsigned)((b)[3] & 7) << 28))

// ---------------------------------------------------------------------------
// Single-wave HMM forward: 8 blocks x 64 threads; each wave owns 16 batch
// rows and the FULL A matrix in registers (operand-swapped MFMA).
//   lane l: li = l&15 (batch row / D-col), h = l>>4 (quarter).
//   D = mfma(A_frag, alpha_frag): col = li = batch, row-state = 16t+4h+r.
// No __syncthreads in the T-loop: a single wave's LDS ops are in-order.
// ---------------------------------------------------------------------------
__global__ void __launch_bounds__(64, 1)
hmm_wave_kernel(const int* __restrict__ obs, const float* __restrict__ I,
                const float* __restrict__ A, const float* __restrict__ Bm,
                float* __restrict__ out)
{
    __shared__ __align__(16) ushort alds[2][16 * NS];  // bf16 alpha, dbuf, swizzled
    __shared__ __align__(16) float  et[NE * 132];      // emissions, padded rows

    const int l  = threadIdx.x;
    const int li = l & 15;          // batch row (and D column)
    const int h  = l >> 4;          // quarter
    const int swz = (li & 7) << 4;  // byte-XOR swizzle per alpha row
    const int brow0 = blockIdx.x * 16;
    const int* orow = obs + (size_t)(brow0 + li) * NT;

    // ---- emission table et[o][s] = Bm[s][o], row stride 132 floats ----
    for (int i = l; i < NE * NS; i += 64)
        et[(i >> 7) * 132 + (i & 127)] = Bm[(i & 127) * NE + (i >> 7)];

    // ---- full A as register A-operand fragments ----
    // bfrag[t][q] elem j = A[k = 32q + 8h + j][state = 16t + li]
    bf16x8 bfrag[8][4];
#pragma unroll
    for (int t = 0; t < 8; ++t)
#pragma unroll
        for (int q = 0; q < 4; ++q) {
            bf16x8 f;
#pragma unroll
            for (int j = 0; j < 8; ++j)
                f[j] = f2bf(A[(size_t)(32 * q + 8 * h + j) * NS + 16 * t + li]);
            bfrag[t][q] = f;
        }
    __syncthreads();   // one-time (et visibility); single wave -> cheap

    // ---- obs window 0 + prefetch window 1 (register-resident, 8 steps) ----
    int32x4 la = *(const int32x4*)(orow);
    int32x4 lb = *(const int32x4*)(orow + 4);
    unsigned pk = PACK8(la, lb);
    la = *(const int32x4*)(orow + 8);
    lb = *(const int32x4*)(orow + 12);

    // ---- t = 0: alpha = I * em_0 (unnormalized) ----
    {
        const int o0 = pk & 15;
        const char* eb = (const char*)et + o0 * 528 + 16 * h;
#pragma unroll
        for (int t = 0; t < 8; ++t) {
            f32x4 iv = *(const f32x4*)((const char*)I + 64 * t + 16 * h);
            f32x4 ev = *(const f32x4*)(eb + 64 * t);
            f32x4 v = iv * ev;
            uint32x2 pr;
            pr[0] = cvtpk(v[0], v[1]);
            pr[1] = cvtpk(v[2], v[3]);
            *(uint32x2*)((char*)alds[0] + ((li * 256 + 32 * t + 8 * h) ^ swz)) = pr;
        }
    }

    float ll  = 0.f;
    int   cur = 0;

    // one time-step: alpha_new = (alpha @ A) * e_o;  o = pk nibble i
    auto STEP = [&](int i, bool resc) {
        const int o = (pk >> (4 * i)) & 15;
        // alpha fragments (B-operand): lane holds alpha[li][k = 32q+8h+j]
        bf16x8 af[4];
#pragma unroll
        for (int q = 0; q < 4; ++q)
            af[q] = *(const bf16x8*)((const char*)alds[cur] +
                    ((li * 256 + 64 * q + 16 * h) ^ swz));
        // emission vector for this lane's batch row (dep on obs only)
        const char* eb = (const char*)et + o * 528 + 16 * h;
        f32x4 ev[8];
#pragma unroll
        for (int t = 0; t < 8; ++t) ev[t] = *(const f32x4*)(eb + 64 * t);

        f32x4 acc[8];
#pragma unroll
        for (int t = 0; t < 8; ++t) acc[t] = (f32x4){0.f, 0.f, 0.f, 0.f};
#pragma unroll
        for (int q = 0; q < 4; ++q)
#pragma unroll
            for (int t = 0; t < 8; ++t)
                acc[t] = MFMA(bfrag[t][q], af[q], acc[t], 0, 0, 0);

#pragma unroll
        for (int t = 0; t < 8; ++t) acc[t] *= ev[t];

        if (resc) {   // per-batch-row Z: in-lane sum + 2 shfl over h-groups
            f32x4 s4 = (acc[0] + acc[1]) + (acc[2] + acc[3])
                     + (acc[4] + acc[5]) + (acc[6] + acc[7]);
            float z = (s4[0] + s4[1]) + (s4[2] + s4[3]);
            z += __shfl_xor(z, 16);
            z += __shfl_xor(z, 32);
            ll += logf(z);
            const float inv = 1.0f / z;
#pragma unroll
            for (int t = 0; t < 8; ++t) acc[t] *= inv;
        }

        // write alpha_new[li][16t+4h .. +3]: 8 packed b64, swizzled
#pragma unroll
        for (int t = 0; t < 8; ++t) {
            uint32x2 pr;
            pr[0] = cvtpk(acc[t][0], acc[t][1]);
            pr[1] = cvtpk(acc[t][2], acc[t][3]);
            *(uint32x2*)((char*)alds[cur ^ 1] +
                         ((li * 256 + 32 * t + 8 * h) ^ swz)) = pr;
        }
        cur ^= 1;
    };

    // window 0: steps t = 1..7 (t=0 was init; no rescale yet)
#pragma unroll
    for (int i = 1; i < 8; ++i) STEP(i, false);

    // windows 1..1023: 8 steps each; rescale at i==0 (t=8w) and at t=8191
    for (int w = 1; w < 1024; ++w) {
        pk = PACK8(la, lb);
        if (w < 1023) {   // prefetch next window's symbols
            la = *(const int32x4*)(orow + 8 * w + 8);
            lb = *(const int32x4*)(orow + 8 * w + 12);
        }
#pragma unroll
        for (int i = 0; i < 8; ++i)
            STEP(i, (i == 0) || (w == 1023 && i == 7));
    }

    // ll telescopes to the full log-likelihood (last step rescaled)
    if (l < 16) out[brow0 + li] = ll;
}

extern "C" void kernel_launch(void* const* d_in, const int* in_sizes, int n_in,
                              void* d_out, int out_size, void* d_ws, size_t ws_size,
                              hipStream_t stream) {
    (void)in_sizes; (void)n_in; (void)d_ws; (void)ws_size; (void)out_size;
    const int*   obs = (const int*)d_in[0];
    const float* I   = (const float*)d_in[1];
    const float* A   = (const float*)d_in[2];
    const float* Bm  = (const float*)d_in[3];
    float*       out = (float*)d_out;

    hipLaunchKernelGGL(hmm_wave_kernel, dim3(NB / 16), dim3(64), 0, stream,
                       obs, I, A, Bm, out);
}

// Round 15
// 3307.781 us; speedup vs baseline: 1.2705x; 1.2705x over previous
//
#include <hip/hip_runtime.h>

#define NB 128      // batch
#define NT 8192     // time steps
#define NS 128      // states
#define NE 6        // alphabet

typedef __attribute__((ext_vector_type(8))) short bf16x8;     // 8 bf16 (4 VGPRs)
typedef __attribute__((ext_vector_type(4))) float f32x4;      // MFMA accumulator
typedef __attribute__((ext_vector_type(4))) int   int32x4;
typedef __attribute__((ext_vector_type(4))) unsigned uint32x4;

#define MFMA __builtin_amdgcn_mfma_f32_16x16x32_bf16

// fp32 -> bf16 RNE (one-time conversions)
__device__ __forceinline__ short f2bf(float v) {
    unsigned u = __float_as_uint(v);
    u += 0x7fffu + ((u >> 16) & 1u);
    return (short)(u >> 16);
}
// packed fp32x2 -> bf16x2 RNE (no builtin on gfx950)
__device__ __forceinline__ unsigned cvtpk(float lo, float hi) {
    unsigned r;
    asm("v_cvt_pk_bf16_f32 %0, %1, %2" : "=v"(r) : "v"(lo), "v"(hi));
    return r;
}

// pack 8 symbols (0..5) into one u32, 4 bits each
#define PACK8(a, b)                                                          \
    ((unsigned)((a)[0] & 7)        | ((unsigned)((a)[1] & 7) << 4) |         \
     ((unsigned)((a)[2] & 7) << 8) | ((unsigned)((a)[3] & 7) << 12) |        \
     ((unsigned)((b)[0] & 7) << 16)| ((unsigned)((b)[1] & 7) << 20) |        \
     ((unsigned)((b)[2] & 7) << 24)| ((unsigned)((b)[3] & 7) << 28))

// ---------------------------------------------------------------------------
// Fully in-register HMM forward. 8 blocks x 1 wave; each wave owns 16 batch
// rows and the full (permuted) A matrix in registers.
//
// Key idea: MFMA B-operand slot K=32q+8h+j is loaded with PHYSICAL state
// phi(K) = 32q + 16*(j>>2) + 4h + (j&3)  (bijective bit-permutation).
// Then lane (li,h)'s D output acc[t][r] (state 16t+4h+r) maps back into its
// OWN next-step B-slots: af[q] = {cvtpk(acc[2q]), cvtpk(acc[2q+1])} — the
// alpha recurrence never touches LDS, shuffles, or barriers.
// Matrix fragments: bfrag[t][q][j] = A[phi][16t + li]  (rows permuted by phi).
// Emission & rescale act on acc's true state labels (16t+4h+r) as in R14.
// ---------------------------------------------------------------------------
__global__ void __launch_bounds__(64, 1)
hmm_reg_kernel(const int* __restrict__ obs, const float* __restrict__ I,
               const float* __restrict__ A, const float* __restrict__ Bm,
               float* __restrict__ out)
{
    __shared__ __align__(16) float et[NE * 132];   // emissions, padded rows

    const int l  = threadIdx.x;
    const int li = l & 15;          // batch row (D column)
    const int h  = l >> 4;          // quarter
    const int brow0 = blockIdx.x * 16;
    const int* orow = obs + (size_t)(brow0 + li) * NT;

    // ---- emission table et[o][s] = Bm[s][o], row stride 132 floats ----
    for (int i = l; i < NE * NS; i += 64)
        et[(i >> 7) * 132 + (i & 127)] = Bm[(i & 127) * NE + (i >> 7)];

    // ---- A as phi-permuted A-operand fragments (128 VGPRs, one-time) ----
    bf16x8 bfrag[8][4];
#pragma unroll
    for (int t = 0; t < 8; ++t)
#pragma unroll
        for (int q = 0; q < 4; ++q) {
            bf16x8 f;
#pragma unroll
            for (int j = 0; j < 8; ++j) {
                const int phi = 32 * q + 16 * (j >> 2) + 4 * h + (j & 3);
                f[j] = f2bf(A[(size_t)phi * NS + 16 * t + li]);
            }
            bfrag[t][q] = f;
        }
    __syncthreads();   // et visibility (one-time)

    // ---- obs window 0 + prefetch window 1 ----
    int32x4 la = *(const int32x4*)(orow);
    int32x4 lb = *(const int32x4*)(orow + 4);
    unsigned pk = PACK8(la, lb);
    la = *(const int32x4*)(orow + 8);
    lb = *(const int32x4*)(orow + 12);

    // ---- t = 0: af[q][j] = bf16(I[phi] * e_{o0}[phi])  (phi-slot layout) ----
    bf16x8 af[4];
    {
        const int o0 = pk & 15;
        const float* eb = et + o0 * 132;
#pragma unroll
        for (int q = 0; q < 4; ++q) {
            bf16x8 f;
#pragma unroll
            for (int j = 0; j < 8; ++j) {
                const int phi = 32 * q + 16 * (j >> 2) + 4 * h + (j & 3);
                f[j] = f2bf(I[phi] * eb[phi]);
            }
            af[q] = f;
        }
    }

    float ll = 0.f;

    // one time-step, entirely in registers
    auto STEP = [&](int i, bool resc) {
        const int o = (pk >> (4 * i)) & 15;
        const char* eb = (const char*)et + o * 528 + 16 * h;
        f32x4 ev[8];
#pragma unroll
        for (int t = 0; t < 8; ++t) ev[t] = *(const f32x4*)(eb + 64 * t);

        const f32x4 z4 = (f32x4){0.f, 0.f, 0.f, 0.f};
        f32x4 acc[8];
#pragma unroll
        for (int t = 0; t < 8; ++t) acc[t] = MFMA(bfrag[t][0], af[0], z4, 0, 0, 0);
#pragma unroll
        for (int q = 1; q < 4; ++q)
#pragma unroll
            for (int t = 0; t < 8; ++t)
                acc[t] = MFMA(bfrag[t][q], af[q], acc[t], 0, 0, 0);

#pragma unroll
        for (int t = 0; t < 8; ++t) acc[t] *= ev[t];

        if (resc) {   // per-batch-row Z: in-lane sum + 2 shfl over h-groups
            f32x4 s4 = ((acc[0] + acc[1]) + (acc[2] + acc[3]))
                     + ((acc[4] + acc[5]) + (acc[6] + acc[7]));
            float z = (s4[0] + s4[1]) + (s4[2] + s4[3]);
            z += __shfl_xor(z, 16);
            z += __shfl_xor(z, 32);
            ll += logf(z);
            const float inv = 1.0f / z;
#pragma unroll
            for (int t = 0; t < 8; ++t) acc[t] *= inv;
        }

        // repack alpha for next step: pure in-lane (phi makes this exact)
#pragma unroll
        for (int q = 0; q < 4; ++q) {
            uint32x4 u;
            u[0] = cvtpk(acc[2 * q][0],     acc[2 * q][1]);
            u[1] = cvtpk(acc[2 * q][2],     acc[2 * q][3]);
            u[2] = cvtpk(acc[2 * q + 1][0], acc[2 * q + 1][1]);
            u[3] = cvtpk(acc[2 * q + 1][2], acc[2 * q + 1][3]);
            af[q] = __builtin_bit_cast(bf16x8, u);
        }
    };

    // window 0: steps t = 1..7 (t=0 was init; no rescale yet)
#pragma unroll
    for (int i = 1; i < 8; ++i) STEP(i, false);

    // windows 1..1023: 8 steps each; rescale at i==0 (t=8w) and at t=8191
    for (int w = 1; w < 1024; ++w) {
        pk = PACK8(la, lb);
        if (w < 1023) {   // prefetch next window's symbols
            la = *(const int32x4*)(orow + 8 * w + 8);
            lb = *(const int32x4*)(orow + 8 * w + 12);
        }
#pragma unroll
        for (int i = 0; i < 8; ++i)
            STEP(i, (i == 0) || (w == 1023 && i == 7));
    }

    // ll telescopes to the full log-likelihood (last step rescaled)
    if (l < 16) out[brow0 + li] = ll;
}

extern "C" void kernel_launch(void* const* d_in, const int* in_sizes, int n_in,
                              void* d_out, int out_size, void* d_ws, size_t ws_size,
                              hipStream_t stream) {
    (void)in_sizes; (void)n_in; (void)d_ws; (void)ws_size; (void)out_size;
    const int*   obs = (const int*)d_in[0];
    const float* I   = (const float*)d_in[1];
    const float* A   = (const float*)d_in[2];
    const float* Bm  = (const float*)d_in[3];
    float*       out = (float*)d_out;

    hipLaunchKernelGGL(hmm_reg_kernel, dim3(NB / 16), dim3(64), 0, stream,
                       obs, I, A, Bm, out);
}

// Round 16
// 1964.293 us; speedup vs baseline: 2.1395x; 1.6840x over previous
//
#include <hip/hip_runtime.h>

#define NB 128      // batch
#define NT 8192     // time steps
#define NS 128      // states
#define NE 6        // alphabet
#define NTRI 2730   // triples covering steps 1..8190; +1 single step at 8191

// ---- workspace layout (bytes) ----
#define G3F_OFF 0
#define G3F_SZ  (36 * 32768)             // 36 triple-matrices, bf16 frag layout
#define AF_OFF  (G3F_OFF + G3F_SZ)       // plain A, frag layout (tail step)
#define AF_SZ   32768
#define SEL_OFF (AF_OFF + AF_SZ)         // per-row selector table
#define SEL_SZ  (NB * (NTRI + 1) * 4)
#define CT_OFF  (SEL_OFF + SEL_SZ)       // C_o fp32 temp (6 x 128 x 128)
#define CT_SZ   (6 * NS * NS * 4)
#define WS_NEED (CT_OFF + CT_SZ)         // ~3.0 MB

typedef __attribute__((ext_vector_type(8))) short bf16x8;
typedef __attribute__((ext_vector_type(4))) float f32x4;
typedef __attribute__((ext_vector_type(4))) unsigned uint32x4;
typedef __attribute__((ext_vector_type(4))) int int32x4;

#define MFMA __builtin_amdgcn_mfma_f32_16x16x32_bf16

__device__ __forceinline__ short f2bf(float v) {
    unsigned u = __float_as_uint(v);
    u += 0x7fffu + ((u >> 16) & 1u);
    return (short)(u >> 16);
}
__device__ __forceinline__ unsigned cvtpk(float lo, float hi) {
    unsigned r;
    asm("v_cvt_pk_bf16_f32 %0, %1, %2" : "=v"(r) : "v"(lo), "v"(hi));
    return r;
}

// ---------------------------------------------------------------------------
// K1: C_o = A * diag(Bm[:,o]) * A, fp32, ws[CT_OFF + o*65536 + k*512 + s*4].
// ---------------------------------------------------------------------------
__global__ void __launch_bounds__(128, 1)
pre_C(const float* __restrict__ A, const float* __restrict__ Bm,
      char* __restrict__ ws)
{
    __shared__ float Af[NS * NS];
    __shared__ float wA[NS * NS];
    const int s = threadIdx.x, m = blockIdx.x, ig = blockIdx.y;
    float* Cw = (float*)(ws + CT_OFF) + m * NS * NS;

    for (int r = 0; r < NS; ++r) Af[r * NS + s] = A[r * NS + s];
    __syncthreads();
    for (int k = 0; k < NS; ++k)
        wA[k * NS + s] = Bm[k * NE + m] * Af[k * NS + s];
    __syncthreads();
    for (int i0 = ig * 32; i0 < ig * 32 + 32; i0 += 4) {
        float a0 = 0.f, a1 = 0.f, a2 = 0.f, a3 = 0.f;
        for (int k = 0; k < NS; ++k) {
            const float wv = wA[k * NS + s];
            a0 = fmaf(Af[(i0 + 0) * NS + k], wv, a0);
            a1 = fmaf(Af[(i0 + 1) * NS + k], wv, a1);
            a2 = fmaf(Af[(i0 + 2) * NS + k], wv, a2);
            a3 = fmaf(Af[(i0 + 3) * NS + k], wv, a3);
        }
        Cw[(i0 + 0) * NS + s] = a0;
        Cw[(i0 + 1) * NS + s] = a1;
        Cw[(i0 + 2) * NS + s] = a2;
        Cw[(i0 + 3) * NS + s] = a3;
    }
}

// ---------------------------------------------------------------------------
// K2: G3_{ab} = C_a * diag(Bm[:,b]) * A  (block m = a*6+b, m<36), bf16 in the
// MFMA fragment layout the main kernel streams; block 36 writes plain A.
// Frag element (t,q, lane l=(h*16+li), j) = G[phi(q,h,j)][16t+li],
// phi = 32q + 16*(j>>2) + 4h + (j&3).  Addr: ((t*4+q)*64 + l)*16 + j*2.
// ---------------------------------------------------------------------------
__global__ void __launch_bounds__(512, 1)
pre_G3(const float* __restrict__ A, const float* __restrict__ Bm,
       char* __restrict__ ws)
{
    __shared__ float CaL[NS * NS];
    __shared__ float WL[NS * NS];
    const int m = blockIdx.x;
    const int tid = threadIdx.x;
    const int s = tid & 127, kq = tid >> 7;   // s = column, kq = k-quarter
    char* outp = ws + ((m < 36) ? (G3F_OFF + m * 32768) : AF_OFF);

    auto EMIT = [&](int k, float v) {
        const int q = k >> 5, hh = (k >> 2) & 3, j = 4 * ((k >> 4) & 1) + (k & 3);
        *(ushort*)(outp + (size_t)((((s >> 4) * 4 + q) * 64 + hh * 16 + (s & 15)) * 16
                                   + j * 2)) = (ushort)f2bf(v);
    };

    if (m == 36) {
        for (int k = kq * 32; k < kq * 32 + 32; ++k)
            EMIT(k, A[k * NS + s]);
        return;
    }
    const int a = m / 6, bsym = m % 6;
    const float* Ca = (const float*)(ws + CT_OFF) + a * NS * NS;
    for (int r = tid; r < NS * NS; r += 512) CaL[r] = Ca[r];
    for (int r = tid; r < NS * NS; r += 512)
        WL[r] = Bm[(r >> 7) * NE + bsym] * A[r];
    __syncthreads();

    for (int k0 = kq * 32; k0 < kq * 32 + 32; k0 += 4) {
        float a0 = 0.f, a1 = 0.f, a2 = 0.f, a3 = 0.f;
        for (int mm = 0; mm < NS; ++mm) {
            const float wv = WL[mm * NS + s];
            a0 = fmaf(CaL[(k0 + 0) * NS + mm], wv, a0);
            a1 = fmaf(CaL[(k0 + 1) * NS + mm], wv, a1);
            a2 = fmaf(CaL[(k0 + 2) * NS + mm], wv, a2);
            a3 = fmaf(CaL[(k0 + 3) * NS + mm], wv, a3);
        }
        EMIT(k0 + 0, a0); EMIT(k0 + 1, a1); EMIT(k0 + 2, a2); EMIT(k0 + 3, a3);
    }
}

// ---------------------------------------------------------------------------
// K3: per-row selector table: sel[b][k] = (o1*6+o2)*32768 | o3 for triple k
// (steps 3k+1..3k+3); entry NTRI is a safe dummy for the tail prefetch.
// ---------------------------------------------------------------------------
__global__ void __launch_bounds__(256, 1)
pre_sel(const int* __restrict__ obs, char* __restrict__ ws)
{
    const int b = blockIdx.x;
    const int* orow = obs + (size_t)b * NT;
    unsigned* sp = (unsigned*)(ws + SEL_OFF) + (size_t)b * (NTRI + 1);
    for (int k = threadIdx.x; k <= NTRI; k += 256) {
        unsigned v = 0;
        if (k < NTRI) {
            const int o1 = orow[3 * k + 1], o2 = orow[3 * k + 2], o3 = orow[3 * k + 3];
            v = (unsigned)((o1 * 6 + o2) * 32768 + o3);
        }
        sp[k] = v;
    }
}

// ---------------------------------------------------------------------------
// Main: 128 blocks x 1 wave; ONE batch row per wave (symbols wave-uniform ->
// stream exactly the needed G3 per triple, double-buffered in registers,
// prefetched one triple ahead).  Alpha recurrence = R15's verified in-register
// phi-recycle; all 16 MFMA columns are identical replicas of the single row.
// ---------------------------------------------------------------------------
__global__ void __launch_bounds__(64, 1)
hmm_tri_kernel(const int* __restrict__ obs, const float* __restrict__ I,
               const float* __restrict__ Bm, const char* __restrict__ ws,
               float* __restrict__ out)
{
    __shared__ __align__(16) float et[NE * 132];
    const int l  = threadIdx.x;
    const int li = l & 15;
    const int h  = l >> 4;
    const int b  = blockIdx.x;
    const int* orow = obs + (size_t)b * NT;
    const char* g3f = ws + G3F_OFF;
    const unsigned* selp = (const unsigned*)(ws + SEL_OFF) + (size_t)b * (NTRI + 1);

    for (int i = l; i < NE * NS; i += 64)
        et[(i >> 7) * 132 + (i & 127)] = Bm[(i & 127) * NE + (i >> 7)];
    __syncthreads();

    // init af (phi-slot layout), identical across li (one row replicated)
    bf16x8 af[4];
    {
        const int o0 = orow[0];
        const float* eb = et + o0 * 132;
#pragma unroll
        for (int q = 0; q < 4; ++q) {
            bf16x8 f;
#pragma unroll
            for (int j = 0; j < 8; ++j) {
                const int phi = 32 * q + 16 * (j >> 2) + 4 * h + (j & 3);
                f[j] = f2bf(I[phi] * eb[phi]);
            }
            af[q] = f;
        }
    }

    bf16x8 bA[8][4], bB[8][4];
    unsigned selCur = selp[0];
    {
        const char* p0 = g3f + (selCur & 0xFFFF8000u) + l * 16;
#pragma unroll
        for (int tq = 0; tq < 32; ++tq)
            bA[tq >> 2][tq & 3] = *(const bf16x8*)(p0 + tq * 1024);
    }

    float ll = 0.f;

#define TRIPLE(USE, PRE, SC, SN, RESC)                                         \
    {                                                                          \
        const char* pn_ = g3f + ((SN) & 0xFFFF8000u) + l * 16;                 \
        _Pragma("unroll")                                                      \
        for (int tq_ = 0; tq_ < 32; ++tq_)                                     \
            PRE[tq_ >> 2][tq_ & 3] = *(const bf16x8*)(pn_ + tq_ * 1024);       \
        const int o_ = (SC) & 7;                                               \
        const char* eb_ = (const char*)et + o_ * 528 + 16 * h;                 \
        const f32x4 z4_ = (f32x4){0.f, 0.f, 0.f, 0.f};                         \
        f32x4 acc[8];                                                          \
        _Pragma("unroll")                                                      \
        for (int t_ = 0; t_ < 8; ++t_)                                         \
            acc[t_] = MFMA(USE[t_][0], af[0], z4_, 0, 0, 0);                   \
        _Pragma("unroll")                                                      \
        for (int q_ = 1; q_ < 4; ++q_)                                         \
            _Pragma("unroll")                                                  \
            for (int t_ = 0; t_ < 8; ++t_)                                     \
                acc[t_] = MFMA(USE[t_][q_], af[q_], acc[t_], 0, 0, 0);         \
        _Pragma("unroll")                                                      \
        for (int t_ = 0; t_ < 8; ++t_)                                         \
            acc[t_] *= *(const f32x4*)(eb_ + 64 * t_);                         \
        if (RESC) {                                                            \
            f32x4 s4_ = ((acc[0] + acc[1]) + (acc[2] + acc[3]))                \
                      + ((acc[4] + acc[5]) + (acc[6] + acc[7]));               \
            float z_ = (s4_[0] + s4_[1]) + (s4_[2] + s4_[3]);                  \
            z_ += __shfl_xor(z_, 16);                                          \
            z_ += __shfl_xor(z_, 32);                                          \
            ll += logf(z_);                                                    \
            const float inv_ = 1.0f / z_;                                      \
            _Pragma("unroll")                                                  \
            for (int t_ = 0; t_ < 8; ++t_) acc[t_] *= inv_;                    \
        }                                                                      \
        _Pragma("unroll")                                                      \
        for (int q_ = 0; q_ < 4; ++q_) {                                       \
            uint32x4 u_;                                                       \
            u_[0] = cvtpk(acc[2 * q_][0],     acc[2 * q_][1]);                 \
            u_[1] = cvtpk(acc[2 * q_][2],     acc[2 * q_][3]);                 \
            u_[2] = cvtpk(acc[2 * q_ + 1][0], acc[2 * q_ + 1][1]);             \
            u_[3] = cvtpk(acc[2 * q_ + 1][2], acc[2 * q_ + 1][3]);             \
            af[q_] = __builtin_bit_cast(bf16x8, u_);                           \
        }                                                                      \
    }

    for (int k = 0; k < NTRI; k += 2) {
        const unsigned selN1 = selp[k + 1];
        TRIPLE(bA, bB, selCur, selN1, false);
        const unsigned selN2 = selp[k + 2];   // k+2 <= NTRI (dummy entry)
        TRIPLE(bB, bA, selN1, selN2, true);
        selCur = selN2;
    }
#undef TRIPLE

    // tail single step t = 8191: alpha @ A, * e_{obs[b][8191]}
    {
        const char* pa = ws + AF_OFF + l * 16;
#pragma unroll
        for (int tq = 0; tq < 32; ++tq)
            bA[tq >> 2][tq & 3] = *(const bf16x8*)(pa + tq * 1024);
        const int ol = orow[NT - 1];
        const char* eb = (const char*)et + ol * 528 + 16 * h;
        const f32x4 z4 = (f32x4){0.f, 0.f, 0.f, 0.f};
        f32x4 acc[8];
#pragma unroll
        for (int t = 0; t < 8; ++t) acc[t] = MFMA(bA[t][0], af[0], z4, 0, 0, 0);
#pragma unroll
        for (int q = 1; q < 4; ++q)
#pragma unroll
            for (int t = 0; t < 8; ++t)
                acc[t] = MFMA(bA[t][q], af[q], acc[t], 0, 0, 0);
#pragma unroll
        for (int t = 0; t < 8; ++t) acc[t] *= *(const f32x4*)(eb + 64 * t);
        f32x4 s4 = ((acc[0] + acc[1]) + (acc[2] + acc[3]))
                 + ((acc[4] + acc[5]) + (acc[6] + acc[7]));
        float z = (s4[0] + s4[1]) + (s4[2] + s4[3]);
        z += __shfl_xor(z, 16);
        z += __shfl_xor(z, 32);
        if (l == 0) out[b] = ll + logf(z);
    }
}

// ---------------------------------------------------------------------------
// Fallback (round-15 kernel, no workspace needed) if ws is too small.
// ---------------------------------------------------------------------------
#define PACK8(a, b)                                                          \
    ((unsigned)((a)[0] & 7)        | ((unsigned)((a)[1] & 7) << 4) |         \
     ((unsigned)((a)[2] & 7) << 8) | ((unsigned)((a)[3] & 7) << 12) |        \
     ((unsigned)((b)[0] & 7) << 16)| ((unsigned)((b)[1] & 7) << 20) |        \
     ((unsigned)((b)[2] & 7) << 24)| ((unsigned)((b)[3] & 7) << 28))

__global__ void __launch_bounds__(64, 1)
hmm_reg_kernel(const int* __restrict__ obs, const float* __restrict__ I,
               const float* __restrict__ A, const float* __restrict__ Bm,
               float* __restrict__ out)
{
    __shared__ __align__(16) float et[NE * 132];
    const int l  = threadIdx.x;
    const int li = l & 15;
    const int h  = l >> 4;
    const int brow0 = blockIdx.x * 16;
    const int* orow = obs + (size_t)(brow0 + li) * NT;

    for (int i = l; i < NE * NS; i += 64)
        et[(i >> 7) * 132 + (i & 127)] = Bm[(i & 127) * NE + (i >> 7)];

    bf16x8 bfrag[8][4];
#pragma unroll
    for (int t = 0; t < 8; ++t)
#pragma unroll
        for (int q = 0; q < 4; ++q) {
            bf16x8 f;
#pragma unroll
            for (int j = 0; j < 8; ++j) {
                const int phi = 32 * q + 16 * (j >> 2) + 4 * h + (j & 3);
                f[j] = f2bf(A[(size_t)phi * NS + 16 * t + li]);
            }
            bfrag[t][q] = f;
        }
    __syncthreads();

    int32x4 la = *(const int32x4*)(orow);
    int32x4 lb = *(const int32x4*)(orow + 4);
    unsigned pk = PACK8(la, lb);
    la = *(const int32x4*)(orow + 8);
    lb = *(const int32x4*)(orow + 12);

    bf16x8 af[4];
    {
        const int o0 = pk & 15;
        const float* eb = et + o0 * 132;
#pragma unroll
        for (int q = 0; q < 4; ++q) {
            bf16x8 f;
#pragma unroll
            for (int j = 0; j < 8; ++j) {
                const int phi = 32 * q + 16 * (j >> 2) + 4 * h + (j & 3);
                f[j] = f2bf(I[phi] * eb[phi]);
            }
            af[q] = f;
        }
    }

    float ll = 0.f;
    auto STEP = [&](int i, bool resc) {
        const int o = (pk >> (4 * i)) & 15;
        const char* eb = (const char*)et + o * 528 + 16 * h;
        f32x4 ev[8];
#pragma unroll
        for (int t = 0; t < 8; ++t) ev[t] = *(const f32x4*)(eb + 64 * t);
        const f32x4 z4 = (f32x4){0.f, 0.f, 0.f, 0.f};
        f32x4 acc[8];
#pragma unroll
        for (int t = 0; t < 8; ++t) acc[t] = MFMA(bfrag[t][0], af[0], z4, 0, 0, 0);
#pragma unroll
        for (int q = 1; q < 4; ++q)
#pragma unroll
            for (int t = 0; t < 8; ++t)
                acc[t] = MFMA(bfrag[t][q], af[q], acc[t], 0, 0, 0);
#pragma unroll
        for (int t = 0; t < 8; ++t) acc[t] *= ev[t];
        if (resc) {
            f32x4 s4 = ((acc[0] + acc[1]) + (acc[2] + acc[3]))
                     + ((acc[4] + acc[5]) + (acc[6] + acc[7]));
            float z = (s4[0] + s4[1]) + (s4[2] + s4[3]);
            z += __shfl_xor(z, 16);
            z += __shfl_xor(z, 32);
            ll += logf(z);
            const float inv = 1.0f / z;
#pragma unroll
            for (int t = 0; t < 8; ++t) acc[t] *= inv;
        }
#pragma unroll
        for (int q = 0; q < 4; ++q) {
            uint32x4 u;
            u[0] = cvtpk(acc[2 * q][0],     acc[2 * q][1]);
            u[1] = cvtpk(acc[2 * q][2],     acc[2 * q][3]);
            u[2] = cvtpk(acc[2 * q + 1][0], acc[2 * q + 1][1]);
            u[3] = cvtpk(acc[2 * q + 1][2], acc[2 * q + 1][3]);
            af[q] = __builtin_bit_cast(bf16x8, u);
        }
    };

#pragma unroll
    for (int i = 1; i < 8; ++i) STEP(i, false);
    for (int w = 1; w < 1024; ++w) {
        pk = PACK8(la, lb);
        if (w < 1023) {
            la = *(const int32x4*)(orow + 8 * w + 8);
            lb = *(const int32x4*)(orow + 8 * w + 12);
        }
#pragma unroll
        for (int i = 0; i < 8; ++i)
            STEP(i, (i == 0) || (w == 1023 && i == 7));
    }
    if (l < 16) out[brow0 + li] = ll;
}

extern "C" void kernel_launch(void* const* d_in, const int* in_sizes, int n_in,
                              void* d_out, int out_size, void* d_ws, size_t ws_size,
                              hipStream_t stream) {
    (void)in_sizes; (void)n_in; (void)out_size;
    const int*   obs = (const int*)d_in[0];
    const float* I   = (const float*)d_in[1];
    const float* A   = (const float*)d_in[2];
    const float* Bm  = (const float*)d_in[3];
    float*       out = (float*)d_out;

    if (ws_size < (size_t)WS_NEED) {
        hipLaunchKernelGGL(hmm_reg_kernel, dim3(NB / 16), dim3(64), 0, stream,
                           obs, I, A, Bm, out);
        return;
    }
    char* ws = (char*)d_ws;
    hipLaunchKernelGGL(pre_C,   dim3(6, 4), dim3(128), 0, stream, A, Bm, ws);
    hipLaunchKernelGGL(pre_G3,  dim3(37),   dim3(512), 0, stream, A, Bm, ws);
    hipLaunchKernelGGL(pre_sel, dim3(NB),   dim3(256), 0, stream, obs, ws);
    hipLaunchKernelGGL(hmm_tri_kernel, dim3(NB), dim3(64), 0, stream,
                       obs, I, Bm, ws, out);
}